// Round 17
// baseline (222.986 us; speedup 1.0000x reference)
//
#include <hip/hip_runtime.h>
#include <hip/hip_fp16.h>
#include <math.h>

static constexpr int C_IN = 32, IC = 4, H = 128, W = 128, G = 49, F = 196;
static constexpr int L = 1024, Q = 16384;
static constexpr float SCALE = 10.f;
static constexpr int B2P_PER_B = 8*5*136*136;  // 739,840 bf16 per batch (7 shifts + pad plane)
static constexpr int SWS = 152;    // sW row stride (u16); 304 B ≡ 48 mod 128 (bank-friendly)

typedef __attribute__((ext_vector_type(8))) short short8;
typedef __attribute__((ext_vector_type(4))) float floatx4;

__device__ __forceinline__ unsigned short f2bf(float f){
  unsigned u = __float_as_uint(f);
  return (unsigned short)((u + 0x7fffu + ((u >> 16) & 1u)) >> 16);
}
__device__ __forceinline__ float bf2f(unsigned short h){
  return __uint_as_float(((unsigned)h) << 16);
}
__device__ __forceinline__ floatx4 mfma16(uint4 a, uint4 b, floatx4 c){
  return __builtin_amdgcn_mfma_f32_16x16x32_bf16(*(short8*)&a, *(short8*)&b, c, 0, 0, 0);
}

// ---- K1: b1 = 3x3 conv (32->4, pad1); b2p = 7 x-shifted bf16 copies of 1x1 conv
__global__ __launch_bounds__(128) void k_front(
    const float* __restrict__ bsrc, const float* __restrict__ w_g, const float* __restrict__ b_g,
    const float* __restrict__ w_t, const float* __restrict__ b_t,
    float* __restrict__ b1, unsigned short* __restrict__ b2p) {
  __shared__ float s_wg[IC*C_IN*9];
  __shared__ float s_wt[IC*C_IN];
  __shared__ float s_bg[IC], s_bt[IC];
  for (int i = threadIdx.x; i < IC*C_IN*9; i += 128) s_wg[i] = w_g[i];
  for (int i = threadIdx.x; i < IC*C_IN; i += 128) s_wt[i] = w_t[i];
  if (threadIdx.x < IC) { s_bg[threadIdx.x] = b_g[threadIdx.x]; s_bt[threadIdx.x] = b_t[threadIdx.x]; }
  __syncthreads();
  int idx = blockIdx.x*128 + threadIdx.x;
  int x = idx & 127, y = (idx>>7) & 127, bb = idx >> 14;
  const float* bp = bsrc + (size_t)bb*C_IN*H*W;
  float a1[IC], a2[IC];
  #pragma unroll
  for (int o=0;o<IC;o++){ a1[o]=s_bg[o]; a2[o]=s_bt[o]; }
  for (int c=0;c<C_IN;c++){
    const float* bc = bp + c*H*W;
    float ctr = bc[y*W+x];
    #pragma unroll
    for (int o=0;o<IC;o++) a2[o] += ctr * s_wt[o*C_IN + c];
    #pragma unroll
    for (int dy=0; dy<3; dy++){
      int yy = y + dy - 1;
      if ((unsigned)yy >= (unsigned)H) continue;
      #pragma unroll
      for (int dx=0; dx<3; dx++){
        int xx = x + dx - 1;
        if ((unsigned)xx >= (unsigned)W) continue;
        float v = bc[yy*W+xx];
        #pragma unroll
        for (int o=0;o<IC;o++) a1[o] += v * s_wg[(o*C_IN + c)*9 + dy*3 + dx];
      }
    }
  }
  unsigned short* bp2 = b2p + (size_t)bb*B2P_PER_B;
  #pragma unroll
  for (int o=0;o<IC;o++){
    b1[((size_t)(bb*IC+o)*H + y)*W + x] = a1[o];
    unsigned short h = f2bf(a2[o]);
    #pragma unroll
    for (int s=0;s<7;s++){
      int u = x + 3 - s;
      if (u >= 0)
        bp2[((s*5 + o)*136 + (y+3))*136 + u] = h;
    }
  }
}

// ---- K2 v2 (R10/R11-proven): xiT hi/lo + meanxi. 4-way g-split, b128 w-tile.
__global__ __launch_bounds__(128) void k_xi(
    const float* __restrict__ b1, const float* __restrict__ w_fc2, const float* __restrict__ b_fc2,
    unsigned short* __restrict__ xiT, float* __restrict__ meanxi) {
  __shared__ float s_wT[196][16];
  __shared__ float s_p[IC*7*136];
  __shared__ float s_red[2][16];
  int tid = threadIdx.x;
  int blk = blockIdx.x;
  int gq = blk & 3, y = (blk >> 2) & 127, bb = blk >> 9;
  int g0 = (gq == 0) ? 0 : (13 + 12*(gq-1));
  int ng = (gq == 0) ? 13 : 12;
  for (int i = tid; i < 196*16; i += 128){
    int f = i >> 4, gi = i & 15;
    s_wT[f][gi] = (gi < ng) ? w_fc2[(size_t)(g0+gi)*196 + f] : 0.f;
  }
  for (int i=tid; i<IC*7*136; i+=128) {
    int col = i % 136; int t = i / 136; int ki = t % 7; int c = t / 7;
    int gy = y - 3 + ki, gx = col - 3;
    float v = 0.f;
    if ((unsigned)gy < (unsigned)H && (unsigned)gx < (unsigned)W && col < 134)
      v = b1[((size_t)(bb*IC+c)*H + gy)*W + gx];
    s_p[i] = v;
  }
  __syncthreads();
  int x = tid;
  float acc[13];
  #pragma unroll
  for (int ai=0; ai<13; ++ai) acc[ai] = (ai < ng) ? b_fc2[g0+ai] : 0.f;
  for (int c=0;c<IC;c++)
    for (int ki=0;ki<7;ki++){
      const float* prow = &s_p[(c*7+ki)*136 + x];
      #pragma unroll
      for (int kj=0;kj<7;kj++){
        float pv = prow[kj];
        int f = c*49 + ki*7 + kj;
        const float4* wr = (const float4*)&s_wT[f][0];
        float4 w0 = wr[0], w1 = wr[1], w2 = wr[2], w3 = wr[3];
        float wv[16] = {w0.x,w0.y,w0.z,w0.w, w1.x,w1.y,w1.z,w1.w,
                        w2.x,w2.y,w2.z,w2.w, w3.x,w3.y,w3.z,w3.w};
        #pragma unroll
        for (int ai=0; ai<13; ++ai) acc[ai] += pv * wv[ai];
      }
    }
  #pragma unroll
  for (int ai=0; ai<13; ++ai) acc[ai] = fmaxf(acc[ai], 0.f);
  #pragma unroll
  for (int ai=0; ai<13; ++ai){
    if (ai >= ng) break;
    float v = acc[ai];
    #pragma unroll
    for (int off=1; off<64; off<<=1) v += __shfl_xor(v, off);
    if ((tid&63)==0) s_red[tid>>6][ai] = v;
  }
  __syncthreads();
  if (tid < ng) atomicAdd(&meanxi[bb*G + g0 + tid], (s_red[0][tid]+s_red[1][tid]) * (1.f/(float)Q));
  unsigned short* xr = xiT + ((size_t)((bb<<14) + y*W + x))*128;
  #pragma unroll
  for (int ai=0; ai<13; ++ai){
    if (ai >= ng) break;
    float w = acc[ai];
    unsigned short h = f2bf(w);
    float l = w - bf2f(h);
    xr[g0+ai] = h;
    xr[64+g0+ai] = f2bf(l);
  }
  if (gq == 3){
    for (int gi=49; gi<64; ++gi){ xr[gi] = 0; xr[64+gi] = 0; }
  }
}

// ---- K4: wiP + rowmean (unchanged) -----------------------------------------
__global__ __launch_bounds__(256) void k_wi(
    const float* __restrict__ b1, const float* __restrict__ w_fc1, const float* __restrict__ b_fc1,
    const float* __restrict__ meanxi,
    unsigned short* __restrict__ wiP, float* __restrict__ rowmean) {
  __shared__ float wt[196*52];
  __shared__ float mxs[64];
  int tid = threadIdx.x;
  for (int i=tid; i<G*F; i+=256){ int g = i/F, f = i%F; wt[f*52 + g] = w_fc1[i]; }
  for (int i=tid; i<F*3; i+=256){ int f = i/3; wt[f*52 + 49 + (i%3)] = 0.f; }
  int pg0 = blockIdx.x*4;
  int bb = pg0 >> 10;
  if (tid < 64) mxs[tid] = (tid < G) ? meanxi[bb*G + tid] : 0.f;
  __syncthreads();
  int wave = tid >> 6, g = tid & 63;
  int pg = pg0 + wave;
  int p = pg & 1023;
  int py = p >> 5, px = p & 31;
  float acc = (g < G) ? b_fc1[g] : 0.f;
  for (int c=0;c<IC;c++){
    const float* bc = b1 + (size_t)(bb*IC+c)*H*W;
    for (int ki=0;ki<7;ki++){
      int yy = py*4 - 1 + ki;
      if ((unsigned)yy >= (unsigned)H) continue;
      const float* wrow = &wt[(c*49 + ki*7)*52 + g];
      #pragma unroll
      for (int kj=0;kj<7;kj++){
        int xx = px*4 - 1 + kj;
        if ((unsigned)xx >= (unsigned)W) continue;
        acc += bc[yy*W+xx] * wrow[kj*52];
      }
    }
  }
  acc = fmaxf(acc, 0.f);
  if (g >= G) acc = 0.f;
  float r = acc * mxs[g];
  #pragma unroll
  for (int off=1; off<64; off<<=1) r += __shfl_xor(r, off);
  if (g == 0) rowmean[pg] = r;
  unsigned short h = f2bf(acc);
  float l = acc - bf2f(h);
  size_t base = (size_t)pg*128;
  wiP[base + g] = h;
  wiP[base + 64 + g] = f2bf(l);
}

// ---- K5: thr[b,p], bias[b,p] (unchanged) -----------------------------------
__global__ __launch_bounds__(256) void k_thrbias(
    const float* __restrict__ bsrc, const float* __restrict__ w_thr, const float* __restrict__ b_thr,
    const float* __restrict__ w_bias, const float* __restrict__ b_bias,
    float* __restrict__ thr, float* __restrict__ bias) {
  int tid = threadIdx.x;
  int c = tid & 31, pl = tid >> 5;
  int pg = blockIdx.x*8 + pl;
  int bb = pg >> 10, p = pg & 1023;
  int py = p >> 5, px = p & 31;
  const float* bc = bsrc + (size_t)(bb*C_IN + c)*H*W;
  float ta = 0.f, ba = 0.f;
  for (int ki=0;ki<7;ki++){
    int yy = py*4 - 1 + ki;
    if ((unsigned)yy >= (unsigned)H) continue;
    #pragma unroll
    for (int kj=0;kj<7;kj++){
      int xx = px*4 - 1 + kj;
      if ((unsigned)xx >= (unsigned)W) continue;
      float v = bc[yy*W+xx];
      ta += v * w_thr[c*49 + ki*7 + kj];
      ba += v * w_bias[c*49 + ki*7 + kj];
    }
  }
  #pragma unroll
  for (int off=1; off<32; off<<=1){ ta += __shfl_xor(ta, off); ba += __shfl_xor(ba, off); }
  if (c == 0) { thr[pg] = ta + b_thr[0]; bias[pg] = ba + b_bias[0]; }
}

// ---- K7: fused attention, 64 p-rows/block, 128-q chunks, online softmax ----
// Templated on NSP (q-splits). grid = 2bb x 16ptb x NSP, 512 thr (8 waves).
// NCH = Q/NSP/128 chunks per block; chunk = one image row (yy = sp*NCH + c).
// LDS ~41.5 KB (R16) -> 2 blocks/CU needs grid > 256: NSP=16 gives 512 blocks
// (R16 lesson: small LDS alone is useless when grid == CU count; R12 proved
// ws_size >= 25.5 MB so the doubled paccT fits).
template<int NSP, int NCH, int LOGNSP>
__global__ __launch_bounds__(512) void k_attn(
    const unsigned short* __restrict__ b2p, const unsigned short* __restrict__ xiT,
    const unsigned short* __restrict__ wiP, const float* __restrict__ thr,
    const float* __restrict__ bias, const float* __restrict__ rowmean,
    __half* __restrict__ paccT, float* __restrict__ pm, float* __restrict__ pd) {
  __shared__ unsigned short sW[2][64*SWS];
  __shared__ float sRed[8][64];
  __shared__ float sAlpha[64];
  int tid = threadIdx.x, lane = tid & 63, wave = tid >> 6;
  int l16 = lane & 15, lg = lane >> 4;
  int wid = blockIdx.x;
  int sp = wid & (NSP-1), ptb = (wid >> LOGNSP) & 15, bb = wid >> (LOGNSP+4);
  int pt2 = wave >> 2, qq = wave & 3;
  int gi0 = (bb<<10) + ptb*64;
  int pl[2] = { pt2*32 + l16, pt2*32 + 16 + l16 };
  float cf[2];
  uint4 wh0[2], wh1[2], wl0[2], wl1[2];
  #pragma unroll
  for (int a=0;a<2;a++){
    int gi = gi0 + pl[a];
    cf[a] = bias[gi] - rowmean[gi]*thr[gi];
    const unsigned short* wr = wiP + (size_t)gi*128;
    wh0[a] = *(const uint4*)&wr[lg*8];
    wh1[a] = *(const uint4*)&wr[32 + lg*8];
    wl0[a] = *(const uint4*)&wr[64 + lg*8];
    wl1[a] = *(const uint4*)&wr[96 + lg*8];
  }
  const unsigned short* xib = xiT + ((size_t)((bb<<14) + sp*(NCH*128) + qq*32))*128;
  int bbase = bb * B2P_PER_B;

  int okf[2]; int At[2]; int fcol[2];
  #pragma unroll
  for (int i=0;i<2;i++){
    int ft = wave + 8*i;
    okf[i] = (ft < 13);
    if (ft > 12) ft = 12;
    int f = ft*16 + l16;
    fcol[i] = f;
    int fc = f/49, rem = f%49, fki = rem/7, fkj = rem%7;
    At[i] = ((fkj*5 + fc)*136 + fki)*136;
  }
  floatx4 acc[2][4];
  #pragma unroll
  for (int i=0;i<2;i++)
    #pragma unroll
    for (int pt=0;pt<4;pt++) acc[i][pt] = (floatx4){0,0,0,0};

  float Mrun[2] = {0.f, 0.f};   // v >= 0 always (s>=0 from relu'd inputs)
  float dpart[2] = {0.f, 0.f};

  for (int c=0; c<NCH; ++c){
    // ---- compute region: rescale (if c>0), scores(c), PV(c-1) ----
    if (c > 0){
      #pragma unroll
      for (int pt=0; pt<4; ++pt){
        float4 av = *(const float4*)&sAlpha[pt*16 + lg*4];
        floatx4 a4 = {av.x, av.y, av.z, av.w};
        acc[0][pt] *= a4;
        acc[1][pt] *= a4;
      }
    }
    float vs[2][8];
    unsigned mb[2] = {0u, 0u};
    float vmax[2] = {0.f, 0.f};
    #pragma unroll
    for (int qt=0; qt<2; ++qt){
      const unsigned short* xr = xib + (size_t)(c*128 + qt*16 + l16)*128;
      uint4 ah0 = *(const uint4*)&xr[lg*8];
      uint4 ah1 = *(const uint4*)&xr[32 + lg*8];
      uint4 al0 = *(const uint4*)&xr[64 + lg*8];
      uint4 al1 = *(const uint4*)&xr[96 + lg*8];
      #pragma unroll
      for (int a=0;a<2;a++){
        floatx4 s4 = {0.f,0.f,0.f,0.f};
        s4 = mfma16(ah0, wh0[a], s4);
        s4 = mfma16(ah1, wh1[a], s4);
        s4 = mfma16(ah0, wl0[a], s4);
        s4 = mfma16(ah1, wl1[a], s4);
        s4 = mfma16(al0, wh0[a], s4);
        s4 = mfma16(al1, wh1[a], s4);
        #pragma unroll
        for (int j=0;j<4;j++){
          float s = s4[j];
          float xm = s + cf[a];
          if (xm > 0.f) mb[a] |= (1u << (qt*4 + j));
          float v = s * fmaxf(xm, 0.f) * SCALE;
          vs[a][qt*4 + j] = v;
          vmax[a] = fmaxf(vmax[a], v);
        }
      }
    }
    if (c > 0){
      int yy = sp*NCH + (c-1);
      const unsigned short* sWr = &sW[(c-1)&1][0];
      #pragma unroll
      for (int ks=0; ks<4; ++ks){
        int kk = ks*32 + lg*8;
        int gb = bbase + yy*136 + kk;
        uint4 bv0 = *(const uint4*)(b2p + gb + At[0]);
        uint4 bv1 = {0,0,0,0};
        if (okf[1]) bv1 = *(const uint4*)(b2p + gb + At[1]);
        #pragma unroll
        for (int pt=0; pt<4; ++pt){
          uint4 a0 = *(const uint4*)&sWr[(pt*16 + l16)*SWS + kk];
          acc[0][pt] = mfma16(a0, bv0, acc[0][pt]);
          if (okf[1]) acc[1][pt] = mfma16(a0, bv1, acc[1][pt]);
        }
      }
    }
    #pragma unroll
    for (int a=0;a<2;a++){
      vmax[a] = fmaxf(vmax[a], __shfl_xor(vmax[a], 16));
      vmax[a] = fmaxf(vmax[a], __shfl_xor(vmax[a], 32));
      if (lg == 0) sRed[wave][pl[a]] = vmax[a];
    }
    __syncthreads();
    // ---- softmax region: block max, alpha, exp, pack -> sW[c&1] ----
    #pragma unroll
    for (int a=0;a<2;a++){
      float cm = fmaxf(fmaxf(sRed[pt2*4+0][pl[a]], sRed[pt2*4+1][pl[a]]),
                       fmaxf(sRed[pt2*4+2][pl[a]], sRed[pt2*4+3][pl[a]]));
      float Mnew = fmaxf(Mrun[a], cm);
      float alpha = __expf(Mrun[a] - Mnew);
      Mrun[a] = Mnew;
      if (qq == 0 && lg == 0) sAlpha[pl[a]] = alpha;
      float sum = 0.f;
      #pragma unroll
      for (int qt=0; qt<2; ++qt){
        float e0 = __expf(vs[a][qt*4+0] - Mnew);
        float e1 = __expf(vs[a][qt*4+1] - Mnew);
        float e2 = __expf(vs[a][qt*4+2] - Mnew);
        float e3 = __expf(vs[a][qt*4+3] - Mnew);
        sum += e0+e1+e2+e3;
        unsigned m4 = mb[a] >> (qt*4);
        unsigned w0 = ((m4&1u)? (unsigned)f2bf(e0):0u) | (((m4&2u)? (unsigned)f2bf(e1):0u)<<16);
        unsigned w1 = ((m4&4u)? (unsigned)f2bf(e2):0u) | (((m4&8u)? (unsigned)f2bf(e3):0u)<<16);
        uint2 pv = {w0, w1};
        *(uint2*)&sW[c&1][pl[a]*SWS + qq*32 + qt*16 + lg*4] = pv;
      }
      dpart[a] = dpart[a]*alpha + sum;
    }
    __syncthreads();
  }
  // ---- final: rescale with last alpha, PV(last) ----
  #pragma unroll
  for (int pt=0; pt<4; ++pt){
    float4 av = *(const float4*)&sAlpha[pt*16 + lg*4];
    floatx4 a4 = {av.x, av.y, av.z, av.w};
    acc[0][pt] *= a4;
    acc[1][pt] *= a4;
  }
  {
    int yy = sp*NCH + (NCH-1);
    const unsigned short* sWr = &sW[(NCH-1)&1][0];
    #pragma unroll
    for (int ks=0; ks<4; ++ks){
      int kk = ks*32 + lg*8;
      int gb = bbase + yy*136 + kk;
      uint4 bv0 = *(const uint4*)(b2p + gb + At[0]);
      uint4 bv1 = {0,0,0,0};
      if (okf[1]) bv1 = *(const uint4*)(b2p + gb + At[1]);
      #pragma unroll
      for (int pt=0; pt<4; ++pt){
        uint4 a0 = *(const uint4*)&sWr[(pt*16 + l16)*SWS + kk];
        acc[0][pt] = mfma16(a0, bv0, acc[0][pt]);
        if (okf[1]) acc[1][pt] = mfma16(a0, bv1, acc[1][pt]);
      }
    }
  }
  // ---- epilogue: d reduce + stores ----
  #pragma unroll
  for (int a=0;a<2;a++){
    dpart[a] += __shfl_xor(dpart[a], 16);
    dpart[a] += __shfl_xor(dpart[a], 32);
    if (lg == 0) sRed[wave][pl[a]] = dpart[a];
  }
  __syncthreads();
  int rowbase = ((bb*16 + ptb)*NSP + sp)*64;
  if (qq == 0 && lg == 0){
    #pragma unroll
    for (int a=0;a<2;a++){
      float D = sRed[pt2*4+0][pl[a]] + sRed[pt2*4+1][pl[a]]
              + sRed[pt2*4+2][pl[a]] + sRed[pt2*4+3][pl[a]];
      pm[rowbase + pl[a]] = Mrun[a];
      pd[rowbase + pl[a]] = D;
    }
  }
  #pragma unroll
  for (int i=0;i<2;i++){
    if (!okf[i] || fcol[i] >= F) continue;
    #pragma unroll
    for (int pt=0; pt<4; ++pt){
      #pragma unroll
      for (int j=0;j<4;j++){
        int row = rowbase + pt*16 + lg*4 + j;
        paccT[(size_t)fcol[i]*(2048*NSP) + row] = __float2half(acc[i][pt][j]);
      }
    }
  }
}

// ---- K8: combine the NSP q-splits (transposed, coalesced) ------------------
template<int NSP>
__global__ __launch_bounds__(256) void k_combine(
    const __half* __restrict__ paccT, const float* __restrict__ pm, const float* __restrict__ pd,
    float* __restrict__ outpfT){
  int i = blockIdx.x*256 + threadIdx.x;
  if (i >= 2*L*F) return;
  int f = i >> 11;
  int pp = i & 2047;
  int bb = pp >> 10, p = pp & 1023;
  int ptb = p >> 6, r = p & 63;
  int base = ((bb*16 + ptb)*NSP)*64 + r;
  float M = 0.f;
  #pragma unroll
  for (int hh=0; hh<NSP; hh++) M = fmaxf(M, pm[base + hh*64]);
  float num = 0.f, den = 0.f;
  #pragma unroll
  for (int hh=0; hh<NSP; hh++){
    float e = __expf(pm[base + hh*64] - M);
    num += e * __half2float(paccT[(size_t)f*(2048*NSP) + base + hh*64]);
    den += e * pd[base + hh*64];
  }
  outpfT[(size_t)f*2048 + pp] = num/den;
}

// ---- K9: fold + count-normalize (transposed reads) -------------------------
__global__ __launch_bounds__(256) void k_fold(const float* __restrict__ outpfT, float* __restrict__ out){
  int i = blockIdx.x*256 + threadIdx.x;
  if (i >= 2*IC*H*W) return;
  int ww = i & 127, hh = (i>>7)&127, c = (i>>14)&3, bb = i>>16;
  int H3 = hh+3, W3 = ww+3;
  int py0 = (H3-3)>>2, py1 = min(31, H3>>2);
  int px0 = (W3-3)>>2, px1 = min(31, W3>>2);
  float s = 0.f; int cnt = 0;
  for (int py=py0; py<=py1; py++){
    int ki = H3 - 4*py;
    for (int px=px0; px<=px1; px++){
      int kj = W3 - 4*px;
      int f = c*49 + ki*7 + kj;
      s += outpfT[(size_t)f*2048 + (bb<<10) + py*32 + px];
      cnt++;
    }
  }
  out[i] = s / (float)cnt;
}

extern "C" void kernel_launch(void* const* d_in, const int* in_sizes, int n_in,
                              void* d_out, int out_size, void* d_ws, size_t ws_size,
                              hipStream_t stream) {
  const float* b      = (const float*)d_in[0];
  const float* w_g    = (const float*)d_in[1];
  const float* b_g    = (const float*)d_in[2];
  const float* w_t    = (const float*)d_in[3];
  const float* b_t    = (const float*)d_in[4];
  const float* w_fc1  = (const float*)d_in[5];
  const float* b_fc1  = (const float*)d_in[6];
  const float* w_fc2  = (const float*)d_in[7];
  const float* b_fc2  = (const float*)d_in[8];
  const float* w_thr  = (const float*)d_in[9];
  const float* b_thr  = (const float*)d_in[10];
  const float* w_bias = (const float*)d_in[11];
  const float* b_bias = (const float*)d_in[12];
  float* out = (float*)d_out;
  float* ws = (float*)d_ws;
  (void)in_sizes; (void)n_in; (void)out_size;

  // common front section (word offsets)
  float* b1      = ws;                                    // 131,072
  unsigned short* b2p = (unsigned short*)(ws + 131072);   // 739,840 w
  unsigned short* xiT = (unsigned short*)(ws + 870912);   // 2,097,152 w
  unsigned short* wiP = (unsigned short*)(ws + 2968064);  // 131,072 w
  float* meanxi  = ws + 3099136;                          // 128
  float* thr     = ws + 3099264;                          // 2048
  float* bias    = ws + 3101312;                          // 2048
  float* rowmean = ws + 3103360;                          // 2048
  float* outpfT  = ws + 870912;                           // alias xiT (dead after k_attn)

  hipMemsetAsync(meanxi, 0, 2*G*sizeof(float), stream);
  hipMemsetAsync(b2p, 0, 2*B2P_PER_B*sizeof(unsigned short), stream);
  k_front  <<<256, 128, 0, stream>>>(b, w_g, b_g, w_t, b_t, b1, b2p);
  k_xi     <<<1024, 128, 0, stream>>>(b1, w_fc2, b_fc2, xiT, meanxi);
  k_wi     <<<512, 256, 0, stream>>>(b1, w_fc1, b_fc1, meanxi, wiP, rowmean);
  k_thrbias<<<256, 256, 0, stream>>>(b, w_thr, b_thr, w_bias, b_bias, thr, bias);

  // NSP=16 needs 3,105,408 + 3,211,264 + 32,768 + 32,768 = 6,382,208 words (25.5 MB)
  const size_t need16 = (size_t)6382208 * 4;
  if (ws_size >= need16) {
    __half* paccT = (__half*)(ws + 3105408);              // 3,211,264 w
    float* pm     = ws + 6316672;                         // 32,768
    float* pd     = ws + 6349440;                         // 32,768
    k_attn<16,8,4><<<512, 512, 0, stream>>>(b2p, xiT, wiP, thr, bias, rowmean, paccT, pm, pd);
    k_combine<16><<<(2*L*F + 255)/256, 256, 0, stream>>>(paccT, pm, pd, outpfT);
  } else {
    __half* paccT = (__half*)(ws + 3105408);              // 1,605,632 w
    float* pm     = ws + 4711040;                         // 16,384
    float* pd     = ws + 4727424;                         // 16,384
    k_attn<8,16,3><<<256, 512, 0, stream>>>(b2p, xiT, wiP, thr, bias, rowmean, paccT, pm, pd);
    k_combine<8><<<(2*L*F + 255)/256, 256, 0, stream>>>(paccT, pm, pd, outpfT);
  }
  k_fold   <<<512, 256, 0, stream>>>(outpfT, out);
}

// Round 19
// 212.882 us; speedup vs baseline: 1.0475x; 1.0475x over previous
//
#include <hip/hip_runtime.h>
#include <hip/hip_fp16.h>
#include <math.h>

static constexpr int C_IN = 32, IC = 4, H = 128, W = 128, G = 49, F = 196;
static constexpr int L = 1024, Q = 16384;
static constexpr float SCALE = 10.f;
static constexpr int NH = 8;       // q-splits (2048 q each)
static constexpr int B2P_PER_B = 8*5*136*136;  // 739,840 bf16 per batch (7 shifts + pad plane)

typedef __attribute__((ext_vector_type(8))) short short8;
typedef __attribute__((ext_vector_type(4))) float floatx4;

__device__ __forceinline__ unsigned short f2bf(float f){
  unsigned u = __float_as_uint(f);
  return (unsigned short)((u + 0x7fffu + ((u >> 16) & 1u)) >> 16);
}
__device__ __forceinline__ float bf2f(unsigned short h){
  return __uint_as_float(((unsigned)h) << 16);
}
__device__ __forceinline__ floatx4 mfma16(uint4 a, uint4 b, floatx4 c){
  return __builtin_amdgcn_mfma_f32_16x16x32_bf16(*(short8*)&a, *(short8*)&b, c, 0, 0, 0);
}

// ---- K1: b1 = 3x3 conv (32->4, pad1); b2p = 7 x-shifted bf16 copies of 1x1 conv
// 256 blocks x 128 thr (R14 lesson: half-GPU grids starve latency-bound kernels).
__global__ __launch_bounds__(128) void k_front(
    const float* __restrict__ bsrc, const float* __restrict__ w_g, const float* __restrict__ b_g,
    const float* __restrict__ w_t, const float* __restrict__ b_t,
    float* __restrict__ b1, unsigned short* __restrict__ b2p) {
  __shared__ float s_wg[IC*C_IN*9];
  __shared__ float s_wt[IC*C_IN];
  __shared__ float s_bg[IC], s_bt[IC];
  for (int i = threadIdx.x; i < IC*C_IN*9; i += 128) s_wg[i] = w_g[i];
  for (int i = threadIdx.x; i < IC*C_IN; i += 128) s_wt[i] = w_t[i];
  if (threadIdx.x < IC) { s_bg[threadIdx.x] = b_g[threadIdx.x]; s_bt[threadIdx.x] = b_t[threadIdx.x]; }
  __syncthreads();
  int idx = blockIdx.x*128 + threadIdx.x;
  int x = idx & 127, y = (idx>>7) & 127, bb = idx >> 14;
  const float* bp = bsrc + (size_t)bb*C_IN*H*W;
  float a1[IC], a2[IC];
  #pragma unroll
  for (int o=0;o<IC;o++){ a1[o]=s_bg[o]; a2[o]=s_bt[o]; }
  for (int c=0;c<C_IN;c++){
    const float* bc = bp + c*H*W;
    float ctr = bc[y*W+x];
    #pragma unroll
    for (int o=0;o<IC;o++) a2[o] += ctr * s_wt[o*C_IN + c];
    #pragma unroll
    for (int dy=0; dy<3; dy++){
      int yy = y + dy - 1;
      if ((unsigned)yy >= (unsigned)H) continue;
      #pragma unroll
      for (int dx=0; dx<3; dx++){
        int xx = x + dx - 1;
        if ((unsigned)xx >= (unsigned)W) continue;
        float v = bc[yy*W+xx];
        #pragma unroll
        for (int o=0;o<IC;o++) a1[o] += v * s_wg[(o*C_IN + c)*9 + dy*3 + dx];
      }
    }
  }
  unsigned short* bp2 = b2p + (size_t)bb*B2P_PER_B;
  #pragma unroll
  for (int o=0;o<IC;o++){
    b1[((size_t)(bb*IC+o)*H + y)*W + x] = a1[o];
    unsigned short h = f2bf(a2[o]);
    #pragma unroll
    for (int s=0;s<7;s++){
      int u = x + 3 - s;
      if (u >= 0)
        bp2[((s*5 + o)*136 + (y+3))*136 + u] = h;
    }
  }
}

// ---- K2 v2 (R10/R11-proven): xiT hi/lo + meanxi. 4-way g-split, b128 w-tile.
__global__ __launch_bounds__(128) void k_xi(
    const float* __restrict__ b1, const float* __restrict__ w_fc2, const float* __restrict__ b_fc2,
    unsigned short* __restrict__ xiT, float* __restrict__ meanxi) {
  __shared__ float s_wT[196][16];
  __shared__ float s_p[IC*7*136];
  __shared__ float s_red[2][16];
  int tid = threadIdx.x;
  int blk = blockIdx.x;
  int gq = blk & 3, y = (blk >> 2) & 127, bb = blk >> 9;
  int g0 = (gq == 0) ? 0 : (13 + 12*(gq-1));
  int ng = (gq == 0) ? 13 : 12;
  for (int i = tid; i < 196*16; i += 128){
    int f = i >> 4, gi = i & 15;
    s_wT[f][gi] = (gi < ng) ? w_fc2[(size_t)(g0+gi)*196 + f] : 0.f;
  }
  for (int i=tid; i<IC*7*136; i+=128) {
    int col = i % 136; int t = i / 136; int ki = t % 7; int c = t / 7;
    int gy = y - 3 + ki, gx = col - 3;
    float v = 0.f;
    if ((unsigned)gy < (unsigned)H && (unsigned)gx < (unsigned)W && col < 134)
      v = b1[((size_t)(bb*IC+c)*H + gy)*W + gx];
    s_p[i] = v;
  }
  __syncthreads();
  int x = tid;
  float acc[13];
  #pragma unroll
  for (int ai=0; ai<13; ++ai) acc[ai] = (ai < ng) ? b_fc2[g0+ai] : 0.f;
  for (int c=0;c<IC;c++)
    for (int ki=0;ki<7;ki++){
      const float* prow = &s_p[(c*7+ki)*136 + x];
      #pragma unroll
      for (int kj=0;kj<7;kj++){
        float pv = prow[kj];
        int f = c*49 + ki*7 + kj;
        const float4* wr = (const float4*)&s_wT[f][0];
        float4 w0 = wr[0], w1 = wr[1], w2 = wr[2], w3 = wr[3];
        float wv[16] = {w0.x,w0.y,w0.z,w0.w, w1.x,w1.y,w1.z,w1.w,
                        w2.x,w2.y,w2.z,w2.w, w3.x,w3.y,w3.z,w3.w};
        #pragma unroll
        for (int ai=0; ai<13; ++ai) acc[ai] += pv * wv[ai];
      }
    }
  #pragma unroll
  for (int ai=0; ai<13; ++ai) acc[ai] = fmaxf(acc[ai], 0.f);
  #pragma unroll
  for (int ai=0; ai<13; ++ai){
    if (ai >= ng) break;
    float v = acc[ai];
    #pragma unroll
    for (int off=1; off<64; off<<=1) v += __shfl_xor(v, off);
    if ((tid&63)==0) s_red[tid>>6][ai] = v;
  }
  __syncthreads();
  if (tid < ng) atomicAdd(&meanxi[bb*G + g0 + tid], (s_red[0][tid]+s_red[1][tid]) * (1.f/(float)Q));
  unsigned short* xr = xiT + ((size_t)((bb<<14) + y*W + x))*128;
  #pragma unroll
  for (int ai=0; ai<13; ++ai){
    if (ai >= ng) break;
    float w = acc[ai];
    unsigned short h = f2bf(w);
    float l = w - bf2f(h);
    xr[g0+ai] = h;
    xr[64+g0+ai] = f2bf(l);
  }
  if (gq == 3){
    for (int gi=49; gi<64; ++gi){ xr[gi] = 0; xr[64+gi] = 0; }
  }
}

// ---- K4: wiP + rowmean (unchanged) -----------------------------------------
__global__ __launch_bounds__(256) void k_wi(
    const float* __restrict__ b1, const float* __restrict__ w_fc1, const float* __restrict__ b_fc1,
    const float* __restrict__ meanxi,
    unsigned short* __restrict__ wiP, float* __restrict__ rowmean) {
  __shared__ float wt[196*52];
  __shared__ float mxs[64];
  int tid = threadIdx.x;
  for (int i=tid; i<G*F; i+=256){ int g = i/F, f = i%F; wt[f*52 + g] = w_fc1[i]; }
  for (int i=tid; i<F*3; i+=256){ int f = i/3; wt[f*52 + 49 + (i%3)] = 0.f; }
  int pg0 = blockIdx.x*4;
  int bb = pg0 >> 10;
  if (tid < 64) mxs[tid] = (tid < G) ? meanxi[bb*G + tid] : 0.f;
  __syncthreads();
  int wave = tid >> 6, g = tid & 63;
  int pg = pg0 + wave;
  int p = pg & 1023;
  int py = p >> 5, px = p & 31;
  float acc = (g < G) ? b_fc1[g] : 0.f;
  for (int c=0;c<IC;c++){
    const float* bc = b1 + (size_t)(bb*IC+c)*H*W;
    for (int ki=0;ki<7;ki++){
      int yy = py*4 - 1 + ki;
      if ((unsigned)yy >= (unsigned)H) continue;
      const float* wrow = &wt[(c*49 + ki*7)*52 + g];
      #pragma unroll
      for (int kj=0;kj<7;kj++){
        int xx = px*4 - 1 + kj;
        if ((unsigned)xx >= (unsigned)W) continue;
        acc += bc[yy*W+xx] * wrow[kj*52];
      }
    }
  }
  acc = fmaxf(acc, 0.f);
  if (g >= G) acc = 0.f;
  float r = acc * mxs[g];
  #pragma unroll
  for (int off=1; off<64; off<<=1) r += __shfl_xor(r, off);
  if (g == 0) rowmean[pg] = r;
  unsigned short h = f2bf(acc);
  float l = acc - bf2f(h);
  size_t base = (size_t)pg*128;
  wiP[base + g] = h;
  wiP[base + 64 + g] = f2bf(l);
}

// ---- K5: thr[b,p], bias[b,p] (unchanged) -----------------------------------
__global__ __launch_bounds__(256) void k_thrbias(
    const float* __restrict__ bsrc, const float* __restrict__ w_thr, const float* __restrict__ b_thr,
    const float* __restrict__ w_bias, const float* __restrict__ b_bias,
    float* __restrict__ thr, float* __restrict__ bias) {
  int tid = threadIdx.x;
  int c = tid & 31, pl = tid >> 5;
  int pg = blockIdx.x*8 + pl;
  int bb = pg >> 10, p = pg & 1023;
  int py = p >> 5, px = p & 31;
  const float* bc = bsrc + (size_t)(bb*C_IN + c)*H*W;
  float ta = 0.f, ba = 0.f;
  for (int ki=0;ki<7;ki++){
    int yy = py*4 - 1 + ki;
    if ((unsigned)yy >= (unsigned)H) continue;
    #pragma unroll
    for (int kj=0;kj<7;kj++){
      int xx = px*4 - 1 + kj;
      if ((unsigned)xx >= (unsigned)W) continue;
      float v = bc[yy*W+xx];
      ta += v * w_thr[c*49 + ki*7 + kj];
      ba += v * w_bias[c*49 + ki*7 + kj];
    }
  }
  #pragma unroll
  for (int off=1; off<32; off<<=1){ ta += __shfl_xor(ta, off); ba += __shfl_xor(ba, off); }
  if (c == 0) { thr[pg] = ta + b_thr[0]; bias[pg] = ba + b_bias[0]; }
}

// ---- K7: fused attention, 64 p-rows/block, ONLINE softmax + dbuf sW --------
// (R11-proven version, 84.2 us, reproduced in R14/R15. Occupancy ledger:
// R12 NSP=16, R13 32-row, R16 small-LDS, R17 small-LDS+NSP16, R18 16-wave —
// all failed to raise waves/CU past 8 or regressed; this structure is the
// empirical optimum for this problem shape.)
__global__ __launch_bounds__(512) void k_attn(
    const unsigned short* __restrict__ b2p, const unsigned short* __restrict__ xiT,
    const unsigned short* __restrict__ wiP, const float* __restrict__ thr,
    const float* __restrict__ bias, const float* __restrict__ rowmean,
    __half* __restrict__ paccT, float* __restrict__ pm, float* __restrict__ pd) {
  __shared__ unsigned short sW[2][64*280];
  __shared__ float sRed[8][64];
  __shared__ float sAlpha[64];
  int tid = threadIdx.x, lane = tid & 63, wave = tid >> 6;
  int l16 = lane & 15, lg = lane >> 4;
  int wid = blockIdx.x;
  int sp = wid & 7, ptb = (wid >> 3) & 15, bb = wid >> 7;
  int pt2 = wave >> 2, qq = wave & 3;
  int gi0 = (bb<<10) + ptb*64;
  int pl[2] = { pt2*32 + l16, pt2*32 + 16 + l16 };
  float cf[2];
  uint4 wh0[2], wh1[2], wl0[2], wl1[2];
  #pragma unroll
  for (int a=0;a<2;a++){
    int gi = gi0 + pl[a];
    cf[a] = bias[gi] - rowmean[gi]*thr[gi];
    const unsigned short* wr = wiP + (size_t)gi*128;
    wh0[a] = *(const uint4*)&wr[lg*8];
    wh1[a] = *(const uint4*)&wr[32 + lg*8];
    wl0[a] = *(const uint4*)&wr[64 + lg*8];
    wl1[a] = *(const uint4*)&wr[96 + lg*8];
  }
  const unsigned short* xib = xiT + ((size_t)((bb<<14) + sp*2048 + qq*64))*128;
  int bbase = bb * B2P_PER_B;

  int okf[2]; int At[2]; int fcol[2];
  #pragma unroll
  for (int i=0;i<2;i++){
    int ft = wave + 8*i;
    okf[i] = (ft < 13);
    if (ft > 12) ft = 12;
    int f = ft*16 + l16;
    fcol[i] = f;
    int fc = f/49, rem = f%49, fki = rem/7, fkj = rem%7;
    At[i] = ((fkj*5 + fc)*136 + fki)*136;
  }
  floatx4 acc[2][4];
  #pragma unroll
  for (int i=0;i<2;i++)
    #pragma unroll
    for (int pt=0;pt<4;pt++) acc[i][pt] = (floatx4){0,0,0,0};

  float Mrun[2] = {0.f, 0.f};
  float dpart[2] = {0.f, 0.f};

  for (int c=0; c<8; ++c){
    if (c > 0){
      #pragma unroll
      for (int pt=0; pt<4; ++pt){
        float4 av = *(const float4*)&sAlpha[pt*16 + lg*4];
        floatx4 a4 = {av.x, av.y, av.z, av.w};
        acc[0][pt] *= a4;
        acc[1][pt] *= a4;
      }
    }
    float vs[2][16];
    unsigned mb[2] = {0u, 0u};
    float vmax[2] = {0.f, 0.f};
    #pragma unroll
    for (int qt=0; qt<4; ++qt){
      const unsigned short* xr = xib + (size_t)(c*256 + qt*16 + l16)*128;
      uint4 ah0 = *(const uint4*)&xr[lg*8];
      uint4 ah1 = *(const uint4*)&xr[32 + lg*8];
      uint4 al0 = *(const uint4*)&xr[64 + lg*8];
      uint4 al1 = *(const uint4*)&xr[96 + lg*8];
      #pragma unroll
      for (int a=0;a<2;a++){
        floatx4 s4 = {0.f,0.f,0.f,0.f};
        s4 = mfma16(ah0, wh0[a], s4);
        s4 = mfma16(ah1, wh1[a], s4);
        s4 = mfma16(ah0, wl0[a], s4);
        s4 = mfma16(ah1, wl1[a], s4);
        s4 = mfma16(al0, wh0[a], s4);
        s4 = mfma16(al1, wh1[a], s4);
        #pragma unroll
        for (int j=0;j<4;j++){
          float s = s4[j];
          float xm = s + cf[a];
          if (xm > 0.f) mb[a] |= (1u << (qt*4 + j));
          float v = s * fmaxf(xm, 0.f) * SCALE;
          vs[a][qt*4 + j] = v;
          vmax[a] = fmaxf(vmax[a], v);
        }
      }
    }
    if (c > 0){
      int ybase = sp*16 + (c-1)*2;
      const unsigned short* sWr = &sW[(c-1)&1][0];
      for (int ks=0; ks<8; ++ks){
        int kk = ks*32 + lg*8;
        int y = ybase + (kk >> 7), x8 = kk & 127;
        int gb = bbase + y*136 + x8;
        uint4 bv0 = *(const uint4*)(b2p + gb + At[0]);
        uint4 bv1 = {0,0,0,0};
        if (okf[1]) bv1 = *(const uint4*)(b2p + gb + At[1]);
        #pragma unroll
        for (int pt=0; pt<4; ++pt){
          uint4 a0 = *(const uint4*)&sWr[(pt*16 + l16)*280 + kk];
          acc[0][pt] = mfma16(a0, bv0, acc[0][pt]);
          if (okf[1]) acc[1][pt] = mfma16(a0, bv1, acc[1][pt]);
        }
      }
    }
    #pragma unroll
    for (int a=0;a<2;a++){
      vmax[a] = fmaxf(vmax[a], __shfl_xor(vmax[a], 16));
      vmax[a] = fmaxf(vmax[a], __shfl_xor(vmax[a], 32));
      if (lg == 0) sRed[wave][pl[a]] = vmax[a];
    }
    __syncthreads();
    #pragma unroll
    for (int a=0;a<2;a++){
      float cm = fmaxf(fmaxf(sRed[pt2*4+0][pl[a]], sRed[pt2*4+1][pl[a]]),
                       fmaxf(sRed[pt2*4+2][pl[a]], sRed[pt2*4+3][pl[a]]));
      float Mnew = fmaxf(Mrun[a], cm);
      float alpha = __expf(Mrun[a] - Mnew);
      Mrun[a] = Mnew;
      if (qq == 0 && lg == 0) sAlpha[pl[a]] = alpha;
      float sum = 0.f;
      #pragma unroll
      for (int qt=0; qt<4; ++qt){
        float e0 = __expf(vs[a][qt*4+0] - Mnew);
        float e1 = __expf(vs[a][qt*4+1] - Mnew);
        float e2 = __expf(vs[a][qt*4+2] - Mnew);
        float e3 = __expf(vs[a][qt*4+3] - Mnew);
        sum += e0+e1+e2+e3;
        unsigned m4 = mb[a] >> (qt*4);
        unsigned w0 = ((m4&1u)? (unsigned)f2bf(e0):0u) | (((m4&2u)? (unsigned)f2bf(e1):0u)<<16);
        unsigned w1 = ((m4&4u)? (unsigned)f2bf(e2):0u) | (((m4&8u)? (unsigned)f2bf(e3):0u)<<16);
        uint2 pv = {w0, w1};
        *(uint2*)&sW[c&1][pl[a]*280 + qq*64 + qt*16 + lg*4] = pv;
      }
      dpart[a] = dpart[a]*alpha + sum;
    }
    __syncthreads();
  }
  #pragma unroll
  for (int pt=0; pt<4; ++pt){
    float4 av = *(const float4*)&sAlpha[pt*16 + lg*4];
    floatx4 a4 = {av.x, av.y, av.z, av.w};
    acc[0][pt] *= a4;
    acc[1][pt] *= a4;
  }
  {
    int ybase = sp*16 + 7*2;
    const unsigned short* sWr = &sW[1][0];
    for (int ks=0; ks<8; ++ks){
      int kk = ks*32 + lg*8;
      int y = ybase + (kk >> 7), x8 = kk & 127;
      int gb = bbase + y*136 + x8;
      uint4 bv0 = *(const uint4*)(b2p + gb + At[0]);
      uint4 bv1 = {0,0,0,0};
      if (okf[1]) bv1 = *(const uint4*)(b2p + gb + At[1]);
      #pragma unroll
      for (int pt=0; pt<4; ++pt){
        uint4 a0 = *(const uint4*)&sWr[(pt*16 + l16)*280 + kk];
        acc[0][pt] = mfma16(a0, bv0, acc[0][pt]);
        if (okf[1]) acc[1][pt] = mfma16(a0, bv1, acc[1][pt]);
      }
    }
  }
  #pragma unroll
  for (int a=0;a<2;a++){
    dpart[a] += __shfl_xor(dpart[a], 16);
    dpart[a] += __shfl_xor(dpart[a], 32);
    if (lg == 0) sRed[wave][pl[a]] = dpart[a];
  }
  __syncthreads();
  int rowbase = ((bb*16 + ptb)*8 + sp)*64;
  if (qq == 0 && lg == 0){
    #pragma unroll
    for (int a=0;a<2;a++){
      float D = sRed[pt2*4+0][pl[a]] + sRed[pt2*4+1][pl[a]]
              + sRed[pt2*4+2][pl[a]] + sRed[pt2*4+3][pl[a]];
      pm[rowbase + pl[a]] = Mrun[a];
      pd[rowbase + pl[a]] = D;
    }
  }
  #pragma unroll
  for (int i=0;i<2;i++){
    if (!okf[i] || fcol[i] >= F) continue;
    #pragma unroll
    for (int pt=0; pt<4; ++pt){
      #pragma unroll
      for (int j=0;j<4;j++){
        int row = rowbase + pt*16 + lg*4 + j;
        paccT[(size_t)fcol[i]*16384 + row] = __float2half(acc[i][pt][j]);
      }
    }
  }
}

// ---- K8: combine the 8 q-splits (transposed, coalesced; 64-row blocks) -----
__global__ __launch_bounds__(256) void k_combine(
    const __half* __restrict__ paccT, const float* __restrict__ pm, const float* __restrict__ pd,
    float* __restrict__ outpfT){
  int i = blockIdx.x*256 + threadIdx.x;
  if (i >= 2*L*F) return;
  int f = i >> 11;
  int pp = i & 2047;
  int bb = pp >> 10, p = pp & 1023;
  int ptb = p >> 6, r = p & 63;
  int base = ((bb*16 + ptb)*8)*64 + r;
  float M = 0.f;
  #pragma unroll
  for (int hh=0; hh<NH; hh++) M = fmaxf(M, pm[base + hh*64]);
  float num = 0.f, den = 0.f;
  #pragma unroll
  for (int hh=0; hh<NH; hh++){
    float e = __expf(pm[base + hh*64] - M);
    num += e * __half2float(paccT[(size_t)f*16384 + base + hh*64]);
    den += e * pd[base + hh*64];
  }
  outpfT[(size_t)f*2048 + pp] = num/den;
}

// ---- K9: fold + count-normalize (transposed reads) -------------------------
__global__ __launch_bounds__(256) void k_fold(const float* __restrict__ outpfT, float* __restrict__ out){
  int i = blockIdx.x*256 + threadIdx.x;
  if (i >= 2*IC*H*W) return;
  int ww = i & 127, hh = (i>>7)&127, c = (i>>14)&3, bb = i>>16;
  int H3 = hh+3, W3 = ww+3;
  int py0 = (H3-3)>>2, py1 = min(31, H3>>2);
  int px0 = (W3-3)>>2, px1 = min(31, W3>>2);
  float s = 0.f; int cnt = 0;
  for (int py=py0; py<=py1; py++){
    int ki = H3 - 4*py;
    for (int px=px0; px<=px1; px++){
      int kj = W3 - 4*px;
      int f = c*49 + ki*7 + kj;
      s += outpfT[(size_t)f*2048 + (bb<<10) + py*32 + px];
      cnt++;
    }
  }
  out[i] = s / (float)cnt;
}

extern "C" void kernel_launch(void* const* d_in, const int* in_sizes, int n_in,
                              void* d_out, int out_size, void* d_ws, size_t ws_size,
                              hipStream_t stream) {
  const float* b      = (const float*)d_in[0];
  const float* w_g    = (const float*)d_in[1];
  const float* b_g    = (const float*)d_in[2];
  const float* w_t    = (const float*)d_in[3];
  const float* b_t    = (const float*)d_in[4];
  const float* w_fc1  = (const float*)d_in[5];
  const float* b_fc1  = (const float*)d_in[6];
  const float* w_fc2  = (const float*)d_in[7];
  const float* b_fc2  = (const float*)d_in[8];
  const float* w_thr  = (const float*)d_in[9];
  const float* b_thr  = (const float*)d_in[10];
  const float* w_bias = (const float*)d_in[11];
  const float* b_bias = (const float*)d_in[12];
  float* out = (float*)d_out;
  float* ws = (float*)d_ws;
  (void)in_sizes; (void)n_in; (void)out_size; (void)ws_size;

  // workspace layout (float-word offsets), total 4,743,808 words = 19.0 MB
  float* b1      = ws;                                    // 131,072
  unsigned short* b2p = (unsigned short*)(ws + 131072);   // 739,840 w
  unsigned short* xiT = (unsigned short*)(ws + 870912);   // 2,097,152 w
  unsigned short* wiP = (unsigned short*)(ws + 2968064);  // 131,072 w
  float* meanxi  = ws + 3099136;                          // 128
  float* thr     = ws + 3099264;                          // 2048
  float* bias    = ws + 3101312;                          // 2048
  float* rowmean = ws + 3103360;                          // 2048
  __half* paccT  = (__half*)(ws + 3105408);               // 1,605,632 w
  float* pm      = ws + 4711040;                          // 16,384
  float* pd      = ws + 4727424;                          // 16,384
  float* outpfT  = ws + 870912;                           // alias xiT (dead after k_attn)

  hipMemsetAsync(meanxi, 0, 2*G*sizeof(float), stream);
  hipMemsetAsync(b2p, 0, 2*B2P_PER_B*sizeof(unsigned short), stream);
  k_front  <<<256, 128, 0, stream>>>(b, w_g, b_g, w_t, b_t, b1, b2p);
  k_xi     <<<1024, 128, 0, stream>>>(b1, w_fc2, b_fc2, xiT, meanxi);
  k_wi     <<<512, 256, 0, stream>>>(b1, w_fc1, b_fc1, meanxi, wiP, rowmean);
  k_thrbias<<<256, 256, 0, stream>>>(b, w_thr, b_thr, w_bias, b_bias, thr, bias);
  k_attn   <<<256, 512, 0, stream>>>(b2p, xiT, wiP, thr, bias, rowmean, paccT, pm, pd);
  k_combine<<<(2*L*F + 255)/256, 256, 0, stream>>>(paccT, pm, pd, outpfT);
  k_fold   <<<512, 256, 0, stream>>>(outpfT, out);
}

// Round 20
// 209.000 us; speedup vs baseline: 1.0669x; 1.0186x over previous
//
#include <hip/hip_runtime.h>
#include <hip/hip_fp16.h>
#include <math.h>

static constexpr int C_IN = 32, IC = 4, H = 128, W = 128, G = 49, F = 196;
static constexpr int L = 1024, Q = 16384;
static constexpr float SCALE = 10.f;
static constexpr int NH = 8;       // q-splits (2048 q each)
static constexpr int B2P_PER_B = 8*5*136*136;  // 739,840 bf16 per batch (7 shifts + pad plane)

typedef __attribute__((ext_vector_type(8))) short short8;
typedef __attribute__((ext_vector_type(4))) float floatx4;

__device__ __forceinline__ unsigned short f2bf(float f){
  unsigned u = __float_as_uint(f);
  return (unsigned short)((u + 0x7fffu + ((u >> 16) & 1u)) >> 16);
}
__device__ __forceinline__ float bf2f(unsigned short h){
  return __uint_as_float(((unsigned)h) << 16);
}
__device__ __forceinline__ floatx4 mfma16(uint4 a, uint4 b, floatx4 c){
  return __builtin_amdgcn_mfma_f32_16x16x32_bf16(*(short8*)&a, *(short8*)&b, c, 0, 0, 0);
}

// ---- K1: b1 = 3x3 conv (32->4, pad1); b2p = 7 x-shifted bf16 copies of 1x1 conv
__global__ __launch_bounds__(128) void k_front(
    const float* __restrict__ bsrc, const float* __restrict__ w_g, const float* __restrict__ b_g,
    const float* __restrict__ w_t, const float* __restrict__ b_t,
    float* __restrict__ b1, unsigned short* __restrict__ b2p) {
  __shared__ float s_wg[IC*C_IN*9];
  __shared__ float s_wt[IC*C_IN];
  __shared__ float s_bg[IC], s_bt[IC];
  for (int i = threadIdx.x; i < IC*C_IN*9; i += 128) s_wg[i] = w_g[i];
  for (int i = threadIdx.x; i < IC*C_IN; i += 128) s_wt[i] = w_t[i];
  if (threadIdx.x < IC) { s_bg[threadIdx.x] = b_g[threadIdx.x]; s_bt[threadIdx.x] = b_t[threadIdx.x]; }
  __syncthreads();
  int idx = blockIdx.x*128 + threadIdx.x;
  int x = idx & 127, y = (idx>>7) & 127, bb = idx >> 14;
  const float* bp = bsrc + (size_t)bb*C_IN*H*W;
  float a1[IC], a2[IC];
  #pragma unroll
  for (int o=0;o<IC;o++){ a1[o]=s_bg[o]; a2[o]=s_bt[o]; }
  for (int c=0;c<C_IN;c++){
    const float* bc = bp + c*H*W;
    float ctr = bc[y*W+x];
    #pragma unroll
    for (int o=0;o<IC;o++) a2[o] += ctr * s_wt[o*C_IN + c];
    #pragma unroll
    for (int dy=0; dy<3; dy++){
      int yy = y + dy - 1;
      if ((unsigned)yy >= (unsigned)H) continue;
      #pragma unroll
      for (int dx=0; dx<3; dx++){
        int xx = x + dx - 1;
        if ((unsigned)xx >= (unsigned)W) continue;
        float v = bc[yy*W+xx];
        #pragma unroll
        for (int o=0;o<IC;o++) a1[o] += v * s_wg[(o*C_IN + c)*9 + dy*3 + dx];
      }
    }
  }
  unsigned short* bp2 = b2p + (size_t)bb*B2P_PER_B;
  #pragma unroll
  for (int o=0;o<IC;o++){
    b1[((size_t)(bb*IC+o)*H + y)*W + x] = a1[o];
    unsigned short h = f2bf(a2[o]);
    #pragma unroll
    for (int s=0;s<7;s++){
      int u = x + 3 - s;
      if (u >= 0)
        bp2[((s*5 + o)*136 + (y+3))*136 + u] = h;
    }
  }
}

// ---- K2 v2 (R10/R11-proven): xiT hi/lo + meanxi. 4-way g-split, b128 w-tile.
__global__ __launch_bounds__(128) void k_xi(
    const float* __restrict__ b1, const float* __restrict__ w_fc2, const float* __restrict__ b_fc2,
    unsigned short* __restrict__ xiT, float* __restrict__ meanxi) {
  __shared__ float s_wT[196][16];
  __shared__ float s_p[IC*7*136];
  __shared__ float s_red[2][16];
  int tid = threadIdx.x;
  int blk = blockIdx.x;
  int gq = blk & 3, y = (blk >> 2) & 127, bb = blk >> 9;
  int g0 = (gq == 0) ? 0 : (13 + 12*(gq-1));
  int ng = (gq == 0) ? 13 : 12;
  for (int i = tid; i < 196*16; i += 128){
    int f = i >> 4, gi = i & 15;
    s_wT[f][gi] = (gi < ng) ? w_fc2[(size_t)(g0+gi)*196 + f] : 0.f;
  }
  for (int i=tid; i<IC*7*136; i+=128) {
    int col = i % 136; int t = i / 136; int ki = t % 7; int c = t / 7;
    int gy = y - 3 + ki, gx = col - 3;
    float v = 0.f;
    if ((unsigned)gy < (unsigned)H && (unsigned)gx < (unsigned)W && col < 134)
      v = b1[((size_t)(bb*IC+c)*H + gy)*W + gx];
    s_p[i] = v;
  }
  __syncthreads();
  int x = tid;
  float acc[13];
  #pragma unroll
  for (int ai=0; ai<13; ++ai) acc[ai] = (ai < ng) ? b_fc2[g0+ai] : 0.f;
  for (int c=0;c<IC;c++)
    for (int ki=0;ki<7;ki++){
      const float* prow = &s_p[(c*7+ki)*136 + x];
      #pragma unroll
      for (int kj=0;kj<7;kj++){
        float pv = prow[kj];
        int f = c*49 + ki*7 + kj;
        const float4* wr = (const float4*)&s_wT[f][0];
        float4 w0 = wr[0], w1 = wr[1], w2 = wr[2], w3 = wr[3];
        float wv[16] = {w0.x,w0.y,w0.z,w0.w, w1.x,w1.y,w1.z,w1.w,
                        w2.x,w2.y,w2.z,w2.w, w3.x,w3.y,w3.z,w3.w};
        #pragma unroll
        for (int ai=0; ai<13; ++ai) acc[ai] += pv * wv[ai];
      }
    }
  #pragma unroll
  for (int ai=0; ai<13; ++ai) acc[ai] = fmaxf(acc[ai], 0.f);
  #pragma unroll
  for (int ai=0; ai<13; ++ai){
    if (ai >= ng) break;
    float v = acc[ai];
    #pragma unroll
    for (int off=1; off<64; off<<=1) v += __shfl_xor(v, off);
    if ((tid&63)==0) s_red[tid>>6][ai] = v;
  }
  __syncthreads();
  if (tid < ng) atomicAdd(&meanxi[bb*G + g0 + tid], (s_red[0][tid]+s_red[1][tid]) * (1.f/(float)Q));
  unsigned short* xr = xiT + ((size_t)((bb<<14) + y*W + x))*128;
  #pragma unroll
  for (int ai=0; ai<13; ++ai){
    if (ai >= ng) break;
    float w = acc[ai];
    unsigned short h = f2bf(w);
    float l = w - bf2f(h);
    xr[g0+ai] = h;
    xr[64+g0+ai] = f2bf(l);
  }
  if (gq == 3){
    for (int gi=49; gi<64; ++gi){ xr[gi] = 0; xr[64+gi] = 0; }
  }
}

// ---- K4: wiP + rowmean (unchanged) -----------------------------------------
__global__ __launch_bounds__(256) void k_wi(
    const float* __restrict__ b1, const float* __restrict__ w_fc1, const float* __restrict__ b_fc1,
    const float* __restrict__ meanxi,
    unsigned short* __restrict__ wiP, float* __restrict__ rowmean) {
  __shared__ float wt[196*52];
  __shared__ float mxs[64];
  int tid = threadIdx.x;
  for (int i=tid; i<G*F; i+=256){ int g = i/F, f = i%F; wt[f*52 + g] = w_fc1[i]; }
  for (int i=tid; i<F*3; i+=256){ int f = i/3; wt[f*52 + 49 + (i%3)] = 0.f; }
  int pg0 = blockIdx.x*4;
  int bb = pg0 >> 10;
  if (tid < 64) mxs[tid] = (tid < G) ? meanxi[bb*G + tid] : 0.f;
  __syncthreads();
  int wave = tid >> 6, g = tid & 63;
  int pg = pg0 + wave;
  int p = pg & 1023;
  int py = p >> 5, px = p & 31;
  float acc = (g < G) ? b_fc1[g] : 0.f;
  for (int c=0;c<IC;c++){
    const float* bc = b1 + (size_t)(bb*IC+c)*H*W;
    for (int ki=0;ki<7;ki++){
      int yy = py*4 - 1 + ki;
      if ((unsigned)yy >= (unsigned)H) continue;
      const float* wrow = &wt[(c*49 + ki*7)*52 + g];
      #pragma unroll
      for (int kj=0;kj<7;kj++){
        int xx = px*4 - 1 + kj;
        if ((unsigned)xx >= (unsigned)W) continue;
        acc += bc[yy*W+xx] * wrow[kj*52];
      }
    }
  }
  acc = fmaxf(acc, 0.f);
  if (g >= G) acc = 0.f;
  float r = acc * mxs[g];
  #pragma unroll
  for (int off=1; off<64; off<<=1) r += __shfl_xor(r, off);
  if (g == 0) rowmean[pg] = r;
  unsigned short h = f2bf(acc);
  float l = acc - bf2f(h);
  size_t base = (size_t)pg*128;
  wiP[base + g] = h;
  wiP[base + 64 + g] = f2bf(l);
}

// ---- K5: thr[b,p], bias[b,p] (unchanged) -----------------------------------
__global__ __launch_bounds__(256) void k_thrbias(
    const float* __restrict__ bsrc, const float* __restrict__ w_thr, const float* __restrict__ b_thr,
    const float* __restrict__ w_bias, const float* __restrict__ b_bias,
    float* __restrict__ thr, float* __restrict__ bias) {
  int tid = threadIdx.x;
  int c = tid & 31, pl = tid >> 5;
  int pg = blockIdx.x*8 + pl;
  int bb = pg >> 10, p = pg & 1023;
  int py = p >> 5, px = p & 31;
  const float* bc = bsrc + (size_t)(bb*C_IN + c)*H*W;
  float ta = 0.f, ba = 0.f;
  for (int ki=0;ki<7;ki++){
    int yy = py*4 - 1 + ki;
    if ((unsigned)yy >= (unsigned)H) continue;
    #pragma unroll
    for (int kj=0;kj<7;kj++){
      int xx = px*4 - 1 + kj;
      if ((unsigned)xx >= (unsigned)W) continue;
      float v = bc[yy*W+xx];
      ta += v * w_thr[c*49 + ki*7 + kj];
      ba += v * w_bias[c*49 + ki*7 + kj];
    }
  }
  #pragma unroll
  for (int off=1; off<32; off<<=1){ ta += __shfl_xor(ta, off); ba += __shfl_xor(ba, off); }
  if (c == 0) { thr[pg] = ta + b_thr[0]; bias[pg] = ba + b_bias[0]; }
}

// ---- K7: fused attention, 64 p-rows/block, ONLINE softmax + dbuf sW --------
// (R11-proven version, 84.2 us, reproduced R14/R15/R19 — unchanged.)
__global__ __launch_bounds__(512) void k_attn(
    const unsigned short* __restrict__ b2p, const unsigned short* __restrict__ xiT,
    const unsigned short* __restrict__ wiP, const float* __restrict__ thr,
    const float* __restrict__ bias, const float* __restrict__ rowmean,
    __half* __restrict__ paccT, float* __restrict__ pm, float* __restrict__ pd) {
  __shared__ unsigned short sW[2][64*280];
  __shared__ float sRed[8][64];
  __shared__ float sAlpha[64];
  int tid = threadIdx.x, lane = tid & 63, wave = tid >> 6;
  int l16 = lane & 15, lg = lane >> 4;
  int wid = blockIdx.x;
  int sp = wid & 7, ptb = (wid >> 3) & 15, bb = wid >> 7;
  int pt2 = wave >> 2, qq = wave & 3;
  int gi0 = (bb<<10) + ptb*64;
  int pl[2] = { pt2*32 + l16, pt2*32 + 16 + l16 };
  float cf[2];
  uint4 wh0[2], wh1[2], wl0[2], wl1[2];
  #pragma unroll
  for (int a=0;a<2;a++){
    int gi = gi0 + pl[a];
    cf[a] = bias[gi] - rowmean[gi]*thr[gi];
    const unsigned short* wr = wiP + (size_t)gi*128;
    wh0[a] = *(const uint4*)&wr[lg*8];
    wh1[a] = *(const uint4*)&wr[32 + lg*8];
    wl0[a] = *(const uint4*)&wr[64 + lg*8];
    wl1[a] = *(const uint4*)&wr[96 + lg*8];
  }
  const unsigned short* xib = xiT + ((size_t)((bb<<14) + sp*2048 + qq*64))*128;
  int bbase = bb * B2P_PER_B;

  int okf[2]; int At[2]; int fcol[2];
  #pragma unroll
  for (int i=0;i<2;i++){
    int ft = wave + 8*i;
    okf[i] = (ft < 13);
    if (ft > 12) ft = 12;
    int f = ft*16 + l16;
    fcol[i] = f;
    int fc = f/49, rem = f%49, fki = rem/7, fkj = rem%7;
    At[i] = ((fkj*5 + fc)*136 + fki)*136;
  }
  floatx4 acc[2][4];
  #pragma unroll
  for (int i=0;i<2;i++)
    #pragma unroll
    for (int pt=0;pt<4;pt++) acc[i][pt] = (floatx4){0,0,0,0};

  float Mrun[2] = {0.f, 0.f};
  float dpart[2] = {0.f, 0.f};

  for (int c=0; c<8; ++c){
    if (c > 0){
      #pragma unroll
      for (int pt=0; pt<4; ++pt){
        float4 av = *(const float4*)&sAlpha[pt*16 + lg*4];
        floatx4 a4 = {av.x, av.y, av.z, av.w};
        acc[0][pt] *= a4;
        acc[1][pt] *= a4;
      }
    }
    float vs[2][16];
    unsigned mb[2] = {0u, 0u};
    float vmax[2] = {0.f, 0.f};
    #pragma unroll
    for (int qt=0; qt<4; ++qt){
      const unsigned short* xr = xib + (size_t)(c*256 + qt*16 + l16)*128;
      uint4 ah0 = *(const uint4*)&xr[lg*8];
      uint4 ah1 = *(const uint4*)&xr[32 + lg*8];
      uint4 al0 = *(const uint4*)&xr[64 + lg*8];
      uint4 al1 = *(const uint4*)&xr[96 + lg*8];
      #pragma unroll
      for (int a=0;a<2;a++){
        floatx4 s4 = {0.f,0.f,0.f,0.f};
        s4 = mfma16(ah0, wh0[a], s4);
        s4 = mfma16(ah1, wh1[a], s4);
        s4 = mfma16(ah0, wl0[a], s4);
        s4 = mfma16(ah1, wl1[a], s4);
        s4 = mfma16(al0, wh0[a], s4);
        s4 = mfma16(al1, wh1[a], s4);
        #pragma unroll
        for (int j=0;j<4;j++){
          float s = s4[j];
          float xm = s + cf[a];
          if (xm > 0.f) mb[a] |= (1u << (qt*4 + j));
          float v = s * fmaxf(xm, 0.f) * SCALE;
          vs[a][qt*4 + j] = v;
          vmax[a] = fmaxf(vmax[a], v);
        }
      }
    }
    if (c > 0){
      int ybase = sp*16 + (c-1)*2;
      const unsigned short* sWr = &sW[(c-1)&1][0];
      for (int ks=0; ks<8; ++ks){
        int kk = ks*32 + lg*8;
        int y = ybase + (kk >> 7), x8 = kk & 127;
        int gb = bbase + y*136 + x8;
        uint4 bv0 = *(const uint4*)(b2p + gb + At[0]);
        uint4 bv1 = {0,0,0,0};
        if (okf[1]) bv1 = *(const uint4*)(b2p + gb + At[1]);
        #pragma unroll
        for (int pt=0; pt<4; ++pt){
          uint4 a0 = *(const uint4*)&sWr[(pt*16 + l16)*280 + kk];
          acc[0][pt] = mfma16(a0, bv0, acc[0][pt]);
          if (okf[1]) acc[1][pt] = mfma16(a0, bv1, acc[1][pt]);
        }
      }
    }
    #pragma unroll
    for (int a=0;a<2;a++){
      vmax[a] = fmaxf(vmax[a], __shfl_xor(vmax[a], 16));
      vmax[a] = fmaxf(vmax[a], __shfl_xor(vmax[a], 32));
      if (lg == 0) sRed[wave][pl[a]] = vmax[a];
    }
    __syncthreads();
    #pragma unroll
    for (int a=0;a<2;a++){
      float cm = fmaxf(fmaxf(sRed[pt2*4+0][pl[a]], sRed[pt2*4+1][pl[a]]),
                       fmaxf(sRed[pt2*4+2][pl[a]], sRed[pt2*4+3][pl[a]]));
      float Mnew = fmaxf(Mrun[a], cm);
      float alpha = __expf(Mrun[a] - Mnew);
      Mrun[a] = Mnew;
      if (qq == 0 && lg == 0) sAlpha[pl[a]] = alpha;
      float sum = 0.f;
      #pragma unroll
      for (int qt=0; qt<4; ++qt){
        float e0 = __expf(vs[a][qt*4+0] - Mnew);
        float e1 = __expf(vs[a][qt*4+1] - Mnew);
        float e2 = __expf(vs[a][qt*4+2] - Mnew);
        float e3 = __expf(vs[a][qt*4+3] - Mnew);
        sum += e0+e1+e2+e3;
        unsigned m4 = mb[a] >> (qt*4);
        unsigned w0 = ((m4&1u)? (unsigned)f2bf(e0):0u) | (((m4&2u)? (unsigned)f2bf(e1):0u)<<16);
        unsigned w1 = ((m4&4u)? (unsigned)f2bf(e2):0u) | (((m4&8u)? (unsigned)f2bf(e3):0u)<<16);
        uint2 pv = {w0, w1};
        *(uint2*)&sW[c&1][pl[a]*280 + qq*64 + qt*16 + lg*4] = pv;
      }
      dpart[a] = dpart[a]*alpha + sum;
    }
    __syncthreads();
  }
  #pragma unroll
  for (int pt=0; pt<4; ++pt){
    float4 av = *(const float4*)&sAlpha[pt*16 + lg*4];
    floatx4 a4 = {av.x, av.y, av.z, av.w};
    acc[0][pt] *= a4;
    acc[1][pt] *= a4;
  }
  {
    int ybase = sp*16 + 7*2;
    const unsigned short* sWr = &sW[1][0];
    for (int ks=0; ks<8; ++ks){
      int kk = ks*32 + lg*8;
      int y = ybase + (kk >> 7), x8 = kk & 127;
      int gb = bbase + y*136 + x8;
      uint4 bv0 = *(const uint4*)(b2p + gb + At[0]);
      uint4 bv1 = {0,0,0,0};
      if (okf[1]) bv1 = *(const uint4*)(b2p + gb + At[1]);
      #pragma unroll
      for (int pt=0; pt<4; ++pt){
        uint4 a0 = *(const uint4*)&sWr[(pt*16 + l16)*280 + kk];
        acc[0][pt] = mfma16(a0, bv0, acc[0][pt]);
        if (okf[1]) acc[1][pt] = mfma16(a0, bv1, acc[1][pt]);
      }
    }
  }
  #pragma unroll
  for (int a=0;a<2;a++){
    dpart[a] += __shfl_xor(dpart[a], 16);
    dpart[a] += __shfl_xor(dpart[a], 32);
    if (lg == 0) sRed[wave][pl[a]] = dpart[a];
  }
  __syncthreads();
  int rowbase = ((bb*16 + ptb)*8 + sp)*64;
  if (qq == 0 && lg == 0){
    #pragma unroll
    for (int a=0;a<2;a++){
      float D = sRed[pt2*4+0][pl[a]] + sRed[pt2*4+1][pl[a]]
              + sRed[pt2*4+2][pl[a]] + sRed[pt2*4+3][pl[a]];
      pm[rowbase + pl[a]] = Mrun[a];
      pd[rowbase + pl[a]] = D;
    }
  }
  #pragma unroll
  for (int i=0;i<2;i++){
    if (!okf[i] || fcol[i] >= F) continue;
    #pragma unroll
    for (int pt=0; pt<4; ++pt){
      #pragma unroll
      for (int j=0;j<4;j++){
        int row = rowbase + pt*16 + lg*4 + j;
        paccT[(size_t)fcol[i]*16384 + row] = __float2half(acc[i][pt][j]);
      }
    }
  }
}

// ---- K8: fused combine + fold. (f,p)->pixel is bijective, so inlining the
// 8-split softmax-combine per tap does each combine exactly once globally;
// kills the outpfT intermediate + one launch (R20).
__global__ __launch_bounds__(256) void k_out(
    const __half* __restrict__ paccT, const float* __restrict__ pm, const float* __restrict__ pd,
    float* __restrict__ out){
  int i = blockIdx.x*256 + threadIdx.x;
  if (i >= 2*IC*H*W) return;
  int ww = i & 127, hh = (i>>7)&127, c = (i>>14)&3, bb = i>>16;
  int H3 = hh+3, W3 = ww+3;
  int py0 = (H3-3)>>2, py1 = min(31, H3>>2);
  int px0 = (W3-3)>>2, px1 = min(31, W3>>2);
  float s = 0.f; int cnt = 0;
  for (int py=py0; py<=py1; py++){
    int ki = H3 - 4*py;
    for (int px=px0; px<=px1; px++){
      int kj = W3 - 4*px;
      int f = c*49 + ki*7 + kj;
      int p = py*32 + px;
      int ptb = p >> 6, r = p & 63;
      int base = ((bb*16 + ptb)*8)*64 + r;
      float M = 0.f;
      #pragma unroll
      for (int hq=0; hq<NH; hq++) M = fmaxf(M, pm[base + hq*64]);
      float num = 0.f, den = 0.f;
      #pragma unroll
      for (int hq=0; hq<NH; hq++){
        float e = __expf(pm[base + hq*64] - M);
        num += e * __half2float(paccT[(size_t)f*16384 + base + hq*64]);
        den += e * pd[base + hq*64];
      }
      s += num/den;
      cnt++;
    }
  }
  out[i] = s / (float)cnt;
}

extern "C" void kernel_launch(void* const* d_in, const int* in_sizes, int n_in,
                              void* d_out, int out_size, void* d_ws, size_t ws_size,
                              hipStream_t stream) {
  const float* b      = (const float*)d_in[0];
  const float* w_g    = (const float*)d_in[1];
  const float* b_g    = (const float*)d_in[2];
  const float* w_t    = (const float*)d_in[3];
  const float* b_t    = (const float*)d_in[4];
  const float* w_fc1  = (const float*)d_in[5];
  const float* b_fc1  = (const float*)d_in[6];
  const float* w_fc2  = (const float*)d_in[7];
  const float* b_fc2  = (const float*)d_in[8];
  const float* w_thr  = (const float*)d_in[9];
  const float* b_thr  = (const float*)d_in[10];
  const float* w_bias = (const float*)d_in[11];
  const float* b_bias = (const float*)d_in[12];
  float* out = (float*)d_out;
  float* ws = (float*)d_ws;
  (void)in_sizes; (void)n_in; (void)out_size; (void)ws_size;

  // workspace layout (float-word offsets), total 4,743,808 words = 19.0 MB
  float* b1      = ws;                                    // 131,072
  unsigned short* b2p = (unsigned short*)(ws + 131072);   // 739,840 w
  unsigned short* xiT = (unsigned short*)(ws + 870912);   // 2,097,152 w
  unsigned short* wiP = (unsigned short*)(ws + 2968064);  // 131,072 w
  float* meanxi  = ws + 3099136;                          // 128
  float* thr     = ws + 3099264;                          // 2048
  float* bias    = ws + 3101312;                          // 2048
  float* rowmean = ws + 3103360;                          // 2048
  __half* paccT  = (__half*)(ws + 3105408);               // 1,605,632 w
  float* pm      = ws + 4711040;                          // 16,384
  float* pd      = ws + 4727424;                          // 16,384

  hipMemsetAsync(meanxi, 0, 2*G*sizeof(float), stream);
  hipMemsetAsync(b2p, 0, 2*B2P_PER_B*sizeof(unsigned short), stream);
  k_front  <<<256, 128, 0, stream>>>(b, w_g, b_g, w_t, b_t, b1, b2p);
  k_xi     <<<1024, 128, 0, stream>>>(b1, w_fc2, b_fc2, xiT, meanxi);
  k_wi     <<<512, 256, 0, stream>>>(b1, w_fc1, b_fc1, meanxi, wiP, rowmean);
  k_thrbias<<<256, 256, 0, stream>>>(b, w_thr, b_thr, w_bias, b_bias, thr, bias);
  k_attn   <<<256, 512, 0, stream>>>(b2p, xiT, wiP, thr, bias, rowmean, paccT, pm, pd);
  k_out    <<<512, 256, 0, stream>>>(paccT, pm, pd, out);
}